// Round 8
// baseline (245.525 us; speedup 1.0000x reference)
//
#include <hip/hip_runtime.h>
#include <hip/hip_cooperative_groups.h>
#include <math.h>

#define NHEAD 4
#define DHEAD 32
#define NPIX  4096
#define CIN   128
#define RP    8   // query row-tiles per wave (128 queries) — proven optimum

typedef __bf16 bf16_t;
typedef __bf16 bf16x8 __attribute__((ext_vector_type(8)));
typedef __bf16 bf16x4 __attribute__((ext_vector_type(4)));
typedef float  f32x4  __attribute__((ext_vector_type(4)));

namespace cg = cooperative_groups;

// 1/sqrt(32) * log2(e): folded into q weights so softmax exp is bare exp2.
constexpr float QSCALE = 0.17677669529663687f * 1.4426950408889634f;

// ---------------------------------------------------------------------------
// Shared device helpers (r7 verbatim).
// ---------------------------------------------------------------------------
__device__ __forceinline__ void ft_load(const ushort* kb0, const ushort* vb0,
                                        int t, bf16x8* kf, bf16x8* vf) {
#pragma unroll
  for (int p = 0; p < 2; ++p) {
#pragma unroll
    for (int s = 0; s < 2; ++s)
      kf[p * 2 + s] = *(const bf16x8*)(kb0 + (size_t)(t * 64 + p * 32 + s * 4) * DHEAD);
#pragma unroll
    for (int dp = 0; dp < 2; ++dp)
      vf[p * 2 + dp] = *(const bf16x8*)(vb0 + (size_t)dp * 16 * NPIX + t * 64 + p * 32);
  }
}

__device__ __forceinline__ void ft_compute(const bf16x8* qf, const bf16x8* kf,
                                           const bf16x8* vf, const bf16x8 ones,
                                           f32x4 O[RP][2], f32x4* Ol) {
  const f32x4 zero = {0.f, 0.f, 0.f, 0.f};
  __builtin_amdgcn_s_setprio(1);
#pragma unroll
  for (int p = 0; p < 2; ++p) {
#pragma unroll
    for (int rp = 0; rp < RP; ++rp) {
      f32x4 sa = __builtin_amdgcn_mfma_f32_16x16x32_bf16(kf[p * 2 + 0], qf[rp], zero, 0, 0, 0);
      f32x4 sb = __builtin_amdgcn_mfma_f32_16x16x32_bf16(kf[p * 2 + 1], qf[rp], zero, 0, 0, 0);
      bf16x8 pf;
#pragma unroll
      for (int r = 0; r < 4; ++r) {
        pf[r]     = (bf16_t)__builtin_amdgcn_exp2f(sa[r]);
        pf[r + 4] = (bf16_t)__builtin_amdgcn_exp2f(sb[r]);
      }
      O[rp][0] = __builtin_amdgcn_mfma_f32_16x16x32_bf16(pf, vf[p * 2 + 0], O[rp][0], 0, 0, 0);
      O[rp][1] = __builtin_amdgcn_mfma_f32_16x16x32_bf16(pf, vf[p * 2 + 1], O[rp][1], 0, 0, 0);
      Ol[rp]   = __builtin_amdgcn_mfma_f32_16x16x32_bf16(pf, ones, Ol[rp], 0, 0, 0);
    }
  }
  __builtin_amdgcn_s_setprio(0);
}

// qkv weight-fragment load + MFMA body, shared by fused and fallback.
// mt_count tiles starting at ot_base; xf/staging already done by caller.
__device__ __forceinline__ void qkv_tiles(
    const float* __restrict__ wqkv, const bf16x8 xf[2][4],
    int ot_base, int mt_count, int bb, int p0, int lane, int n, int quad,
    ushort* __restrict__ qb, ushort* __restrict__ kb, ushort* __restrict__ vT) {
  for (int mt = 0; mt < mt_count; ++mt) {
    const int ot = ot_base + mt;       // 0..23
    const int type = ot >> 3;          // 0=q 1=k 2=v
    const int wt = ot & 7, head = wt >> 1, d0 = (wt & 1) * 16;
    const int bh = bb * NHEAD + head;
    const float sc = (type == 0) ? QSCALE : 1.f;
    bf16x8 wf4[4];
#pragma unroll
    for (int k = 0; k < 4; ++k) {
      const float* ws = wqkv + (size_t)(ot * 16 + n) * CIN + k * 32 + quad * 8;
      float4 a = *(const float4*)ws;
      float4 b = *(const float4*)(ws + 4);
      wf4[k] = (bf16x8){(bf16_t)(a.x * sc), (bf16_t)(a.y * sc),
                        (bf16_t)(a.z * sc), (bf16_t)(a.w * sc),
                        (bf16_t)(b.x * sc), (bf16_t)(b.y * sc),
                        (bf16_t)(b.z * sc), (bf16_t)(b.w * sc)};
    }
    f32x4 acc[2] = {{0.f, 0.f, 0.f, 0.f}, {0.f, 0.f, 0.f, 0.f}};
    if (type < 2) {
#pragma unroll
      for (int k = 0; k < 4; ++k)
#pragma unroll
        for (int nt = 0; nt < 2; ++nt)
          acc[nt] = __builtin_amdgcn_mfma_f32_16x16x32_bf16(wf4[k], xf[nt][k], acc[nt], 0, 0, 0);
      ushort* dst = (type == 0) ? qb : kb;
#pragma unroll
      for (int nt = 0; nt < 2; ++nt) {  // C[m=oc][n=px] -> [p][d] b64
        bf16x4 o = {(bf16_t)acc[nt][0], (bf16_t)acc[nt][1],
                    (bf16_t)acc[nt][2], (bf16_t)acc[nt][3]};
        *(bf16x4*)(dst + ((size_t)bh * NPIX + p0 + nt * 16 + n) * DHEAD + d0 + quad * 4) = o;
      }
    } else {
#pragma unroll
      for (int k = 0; k < 4; ++k)
#pragma unroll
        for (int nt = 0; nt < 2; ++nt)
          acc[nt] = __builtin_amdgcn_mfma_f32_16x16x32_bf16(xf[nt][k], wf4[k], acc[nt], 0, 0, 0);
#pragma unroll
      for (int nt = 0; nt < 2; ++nt) {  // C[m=px][n=d] -> vT[d][p] b64
        bf16x4 o = {(bf16_t)acc[nt][0], (bf16_t)acc[nt][1],
                    (bf16_t)acc[nt][2], (bf16_t)acc[nt][3]};
        *(bf16x4*)(vT + ((size_t)bh * DHEAD + d0 + n) * NPIX + p0 + nt * 16 + quad * 4) = o;
      }
    }
  }
}

// ---------------------------------------------------------------------------
// r18: single cooperative kernel — qkv | grid.sync | flash | grid.sync | out.
// 512 blocks x 256 thr = exactly 2 blocks/CU co-resident (LDS 73.7 KB,
// ~224 regs at launch_bounds(256,2)).  Eliminates 2 dispatch boundaries
// (launch latency + drain + cache flush).  Phase bodies are r7 verbatim.
// ---------------------------------------------------------------------------
__global__ void __launch_bounds__(256, 2) fused_attn(
    const float* __restrict__ x, const float* __restrict__ wqkv,
    const float* __restrict__ wout, const float* __restrict__ bias,
    ushort* __restrict__ qb, ushort* __restrict__ kb,
    ushort* __restrict__ vT, ushort* __restrict__ ao,
    float* __restrict__ out) {
  __shared__ union {
    ushort xls[32 * 136];              // phase 1 staging (8.7 KB)
    float  ols[4 * 128 * 36];          // phase 2 partials (73.7 KB)
  } sm;

  const int tid = threadIdx.x, wave = tid >> 6, lane = tid & 63;
  const int n = lane & 15, quad = lane >> 4;
  const int blk = blockIdx.x;

  // ===== phase 1: QKV projection (512 blocks, 6 tiles/wave) =====
  {
    const int bb = blk >> 7, p0 = (blk & 127) * 32;
    {  // stage x[bb][c][p0..p0+31] -> xls[p][c] bf16 (4x4 transpose)
      const int pc = tid & 7, c0 = (tid >> 3) * 4;
      const float* xp = x + ((size_t)bb * CIN + c0) * NPIX + p0 + pc * 4;
      float4 r0 = *(const float4*)xp;
      float4 r1 = *(const float4*)(xp + NPIX);
      float4 r2 = *(const float4*)(xp + 2 * NPIX);
      float4 r3 = *(const float4*)(xp + 3 * NPIX);
      bf16x4 w0 = {(bf16_t)r0.x, (bf16_t)r1.x, (bf16_t)r2.x, (bf16_t)r3.x};
      bf16x4 w1 = {(bf16_t)r0.y, (bf16_t)r1.y, (bf16_t)r2.y, (bf16_t)r3.y};
      bf16x4 w2 = {(bf16_t)r0.z, (bf16_t)r1.z, (bf16_t)r2.z, (bf16_t)r3.z};
      bf16x4 w3 = {(bf16_t)r0.w, (bf16_t)r1.w, (bf16_t)r2.w, (bf16_t)r3.w};
      *(bf16x4*)&sm.xls[(pc * 4 + 0) * 136 + c0] = w0;
      *(bf16x4*)&sm.xls[(pc * 4 + 1) * 136 + c0] = w1;
      *(bf16x4*)&sm.xls[(pc * 4 + 2) * 136 + c0] = w2;
      *(bf16x4*)&sm.xls[(pc * 4 + 3) * 136 + c0] = w3;
    }
    __syncthreads();
    bf16x8 xf[2][4];
#pragma unroll
    for (int nt = 0; nt < 2; ++nt)
#pragma unroll
      for (int k = 0; k < 4; ++k)
        xf[nt][k] = *(const bf16x8*)&sm.xls[(nt * 16 + n) * 136 + k * 32 + quad * 8];
    qkv_tiles(wqkv, xf, wave * 6, 6, bb, p0, lane, n, quad, qb, kb, vT);
  }

  cg::this_grid().sync();

  // ===== phase 2: flash attention (r17 core, intra-block key split) =====
  {
    const int bh = blk & 15;
    const int qblk = blk >> 4;
    const int js = wave;
    const int qrel = qblk * 128;

    const ushort* kg = kb + (size_t)bh * NPIX * DHEAD;
    const ushort* vg = vT + (size_t)bh * DHEAD * NPIX;

    bf16x8 qf[RP];
#pragma unroll
    for (int rp = 0; rp < RP; ++rp)
      qf[rp] = *(const bf16x8*)(qb +
          ((size_t)bh * NPIX + qrel + rp * 16 + n) * DHEAD + quad * 8);

    f32x4 O[RP][2], Ol[RP];
#pragma unroll
    for (int rp = 0; rp < RP; ++rp) {
      O[rp][0] = (f32x4){0.f, 0.f, 0.f, 0.f};
      O[rp][1] = (f32x4){0.f, 0.f, 0.f, 0.f};
      Ol[rp]   = (f32x4){0.f, 0.f, 0.f, 0.f};
    }
    const bf16_t one = (bf16_t)1.0f;
    const bf16x8 ones = {one, one, one, one, one, one, one, one};

    const int pk = ((n >> 2) << 3) | (n & 3);
    const ushort* kb0 = kg + (size_t)(js * 1024 + pk) * DHEAD + quad * 8;
    const ushort* vb0 = vg + (size_t)n * NPIX + js * 1024 + quad * 8;

    bf16x8 kA[4], vA[4], kB[4], vB[4];
    ft_load(kb0, vb0, 0, kA, vA);
#pragma unroll 1
    for (int t = 0; t < 16; t += 2) {
      ft_load(kb0, vb0, t + 1, kB, vB);
      ft_compute(qf, kA, vA, ones, O, Ol);
      if (t + 2 < 16) ft_load(kb0, vb0, t + 2, kA, vA);
      ft_compute(qf, kB, vB, ones, O, Ol);
    }

    {  // partials -> LDS
      float* pb = &sm.ols[wave * 128 * 36];
#pragma unroll
      for (int rp = 0; rp < RP; ++rp)
#pragma unroll
        for (int r = 0; r < 4; ++r) {
          const int q = rp * 16 + quad * 4 + r;
          pb[q * 36 + n]      = O[rp][0][r];
          pb[q * 36 + 16 + n] = O[rp][1][r];
          if (n == 0) pb[q * 36 + 32] = Ol[rp][r];
        }
    }
    __syncthreads();

    {  // combine 4 wave-partials, normalize, cast, store bf16 ao
      const int q = tid >> 1, dh = tid & 1;
      f32x4 A0 = {0.f, 0.f, 0.f, 0.f}, A1 = A0, A2 = A0, A3 = A0;
      float l = 0.f;
#pragma unroll
      for (int w = 0; w < 4; ++w) {
        const float* pp = &sm.ols[(w * 128 + q) * 36 + dh * 16];
        A0 += *(const f32x4*)pp;
        A1 += *(const f32x4*)(pp + 4);
        A2 += *(const f32x4*)(pp + 8);
        A3 += *(const f32x4*)(pp + 12);
        l += pp[32 - dh * 16];
      }
      const float inv = 1.f / l;
      bf16x8 o0, o1;
#pragma unroll
      for (int e = 0; e < 4; ++e) {
        o0[e]     = (bf16_t)(A0[e] * inv);
        o0[e + 4] = (bf16_t)(A1[e] * inv);
        o1[e]     = (bf16_t)(A2[e] * inv);
        o1[e + 4] = (bf16_t)(A3[e] * inv);
      }
      ushort* dst = ao + ((size_t)((bh >> 2) * NPIX + qrel + q) * CIN
                          + (bh & 3) * 32 + dh * 16);
      *(bf16x8*)dst = o0;
      *(bf16x8*)(dst + 8) = o1;
    }
  }

  cg::this_grid().sync();

  // ===== phase 3: out projection (two 16-px halves per block) =====
  {
    const int bb = blk >> 7, base = (blk & 127) * 32;
    const int oc0 = wave * 32;

    bf16x8 wf[2][4];
#pragma unroll
    for (int mt = 0; mt < 2; ++mt)
#pragma unroll
      for (int k = 0; k < 4; ++k) {
        const float* ws = wout + (size_t)((wave * 2 + mt) * 16 + n) * CIN + k * 32 + quad * 8;
        float4 a = *(const float4*)ws;
        float4 b = *(const float4*)(ws + 4);
        wf[mt][k] = (bf16x8){(bf16_t)a.x, (bf16_t)a.y, (bf16_t)a.z, (bf16_t)a.w,
                             (bf16_t)b.x, (bf16_t)b.y, (bf16_t)b.z, (bf16_t)b.w};
      }

#pragma unroll
    for (int hh = 0; hh < 2; ++hh) {
      const int p0 = base + hh * 16;
      bf16x8 bfr[4];
#pragma unroll
      for (int k = 0; k < 4; ++k)
        bfr[k] = *(const bf16x8*)(ao +
            ((size_t)(bb * NPIX + p0 + n) * CIN + k * 32 + quad * 8));

      f32x4 acc[2];
#pragma unroll
      for (int mt = 0; mt < 2; ++mt) acc[mt] = (f32x4){0.f, 0.f, 0.f, 0.f};
#pragma unroll
      for (int k = 0; k < 4; ++k)
#pragma unroll
        for (int mt = 0; mt < 2; ++mt)
          acc[mt] = __builtin_amdgcn_mfma_f32_16x16x32_bf16(
              wf[mt][k], bfr[k], acc[mt], 0, 0, 0);

#pragma unroll
      for (int mt = 0; mt < 2; ++mt) {
        const int oc = oc0 + mt * 16 + quad * 4;
#pragma unroll
        for (int r = 0; r < 4; ++r)
          out[((size_t)bb * CIN + oc + r) * NPIX + p0 + n] =
              acc[mt][r] + bias[oc + r];
      }
    }
  }
}

// ---------------------------------------------------------------------------
// Fallback path: r7's three dispatches, verbatim (used only if the
// cooperative launch is rejected by the runtime / capture).
// ---------------------------------------------------------------------------
__global__ void __launch_bounds__(256) qkv_mfma(
    const float* __restrict__ x, const float* __restrict__ wqkv,
    ushort* __restrict__ qb, ushort* __restrict__ kb, ushort* __restrict__ vT) {
  __shared__ ushort Xls[32 * 136];
  const int blk = blockIdx.x, tid = threadIdx.x;
  const int half = blockIdx.y;
  const int wave = tid >> 6, lane = tid & 63;
  const int n = lane & 15, quad = lane >> 4;
  const int bb = blk >> 7;
  const int p0 = (blk & 127) * 32;

  {
    const int pc = tid & 7, c0 = (tid >> 3) * 4;
    const float* xp = x + ((size_t)bb * CIN + c0) * NPIX + p0 + pc * 4;
    float4 r0 = *(const float4*)xp;
    float4 r1 = *(const float4*)(xp + NPIX);
    float4 r2 = *(const float4*)(xp + 2 * NPIX);
    float4 r3 = *(const float4*)(xp + 3 * NPIX);
    bf16x4 w0 = {(bf16_t)r0.x, (bf16_t)r1.x, (bf16_t)r2.x, (bf16_t)r3.x};
    bf16x4 w1 = {(bf16_t)r0.y, (bf16_t)r1.y, (bf16_t)r2.y, (bf16_t)r3.y};
    bf16x4 w2 = {(bf16_t)r0.z, (bf16_t)r1.z, (bf16_t)r2.z, (bf16_t)r3.z};
    bf16x4 w3 = {(bf16_t)r0.w, (bf16_t)r1.w, (bf16_t)r2.w, (bf16_t)r3.w};
    *(bf16x4*)&Xls[(pc * 4 + 0) * 136 + c0] = w0;
    *(bf16x4*)&Xls[(pc * 4 + 1) * 136 + c0] = w1;
    *(bf16x4*)&Xls[(pc * 4 + 2) * 136 + c0] = w2;
    *(bf16x4*)&Xls[(pc * 4 + 3) * 136 + c0] = w3;
  }
  __syncthreads();

  bf16x8 xf[2][4];
#pragma unroll
  for (int nt = 0; nt < 2; ++nt)
#pragma unroll
    for (int k = 0; k < 4; ++k)
      xf[nt][k] = *(const bf16x8*)&Xls[(nt * 16 + n) * 136 + k * 32 + quad * 8];

  qkv_tiles(wqkv, xf, half * 12 + wave * 3, 3, bb, p0, lane, n, quad, qb, kb, vT);
}

__global__ void __launch_bounds__(256, 2) flash_mfma(
    const ushort* __restrict__ qb, const ushort* __restrict__ kbuf,
    const ushort* __restrict__ vTb, ushort* __restrict__ ao) {
  __shared__ float Ols[4 * 128 * 36];
  const int tid = threadIdx.x, wave = tid >> 6, lane = tid & 63;
  const int n = lane & 15, quad = lane >> 4;

  const int id = blockIdx.x;
  const int bh = id & 15;
  const int qblk = id >> 4;
  const int js = wave;
  const int qrel = qblk * 128;

  const ushort* kg = kbuf + (size_t)bh * NPIX * DHEAD;
  const ushort* vg = vTb + (size_t)bh * DHEAD * NPIX;

  bf16x8 qf[RP];
#pragma unroll
  for (int rp = 0; rp < RP; ++rp)
    qf[rp] = *(const bf16x8*)(qb +
        ((size_t)bh * NPIX + qrel + rp * 16 + n) * DHEAD + quad * 8);

  f32x4 O[RP][2], Ol[RP];
#pragma unroll
  for (int rp = 0; rp < RP; ++rp) {
    O[rp][0] = (f32x4){0.f, 0.f, 0.f, 0.f};
    O[rp][1] = (f32x4){0.f, 0.f, 0.f, 0.f};
    Ol[rp]   = (f32x4){0.f, 0.f, 0.f, 0.f};
  }
  const bf16_t one = (bf16_t)1.0f;
  const bf16x8 ones = {one, one, one, one, one, one, one, one};

  const int pk = ((n >> 2) << 3) | (n & 3);
  const ushort* kb0 = kg + (size_t)(js * 1024 + pk) * DHEAD + quad * 8;
  const ushort* vb0 = vg + (size_t)n * NPIX + js * 1024 + quad * 8;

  bf16x8 kA[4], vA[4], kB[4], vB[4];
  ft_load(kb0, vb0, 0, kA, vA);
#pragma unroll 1
  for (int t = 0; t < 16; t += 2) {
    ft_load(kb0, vb0, t + 1, kB, vB);
    ft_compute(qf, kA, vA, ones, O, Ol);
    if (t + 2 < 16) ft_load(kb0, vb0, t + 2, kA, vA);
    ft_compute(qf, kB, vB, ones, O, Ol);
  }

  {
    float* pb = &Ols[wave * 128 * 36];
#pragma unroll
    for (int rp = 0; rp < RP; ++rp)
#pragma unroll
      for (int r = 0; r < 4; ++r) {
        const int q = rp * 16 + quad * 4 + r;
        pb[q * 36 + n]      = O[rp][0][r];
        pb[q * 36 + 16 + n] = O[rp][1][r];
        if (n == 0) pb[q * 36 + 32] = Ol[rp][r];
      }
  }
  __syncthreads();

  {
    const int q = tid >> 1, dh = tid & 1;
    f32x4 A0 = {0.f, 0.f, 0.f, 0.f}, A1 = A0, A2 = A0, A3 = A0;
    float l = 0.f;
#pragma unroll
    for (int w = 0; w < 4; ++w) {
      const float* pp = &Ols[(w * 128 + q) * 36 + dh * 16];
      A0 += *(const f32x4*)pp;
      A1 += *(const f32x4*)(pp + 4);
      A2 += *(const f32x4*)(pp + 8);
      A3 += *(const f32x4*)(pp + 12);
      l += pp[32 - dh * 16];
    }
    const float inv = 1.f / l;
    bf16x8 o0, o1;
#pragma unroll
    for (int e = 0; e < 4; ++e) {
      o0[e]     = (bf16_t)(A0[e] * inv);
      o0[e + 4] = (bf16_t)(A1[e] * inv);
      o1[e]     = (bf16_t)(A2[e] * inv);
      o1[e + 4] = (bf16_t)(A3[e] * inv);
    }
    ushort* dst = ao + ((size_t)((bh >> 2) * NPIX + qrel + q) * CIN
                        + (bh & 3) * 32 + dh * 16);
    *(bf16x8*)dst = o0;
    *(bf16x8*)(dst + 8) = o1;
  }
}

__global__ void __launch_bounds__(256) out_fused(
    const ushort* __restrict__ ao, const float* __restrict__ wout,
    const float* __restrict__ bias, float* __restrict__ out) {
  const int blk = blockIdx.x, tid = threadIdx.x;
  const int wave = tid >> 6, lane = tid & 63;
  const int n = lane & 15, quad = lane >> 4;
  const int bb = blk >> 8;
  const int p0 = (blk & 255) * 16;
  const int oc0 = wave * 32;

  bf16x8 wf[2][4];
#pragma unroll
  for (int mt = 0; mt < 2; ++mt)
#pragma unroll
    for (int k = 0; k < 4; ++k) {
      const float* ws = wout + (size_t)((wave * 2 + mt) * 16 + n) * CIN + k * 32 + quad * 8;
      float4 a = *(const float4*)ws;
      float4 b = *(const float4*)(ws + 4);
      wf[mt][k] = (bf16x8){(bf16_t)a.x, (bf16_t)a.y, (bf16_t)a.z, (bf16_t)a.w,
                           (bf16_t)b.x, (bf16_t)b.y, (bf16_t)b.z, (bf16_t)b.w};
    }

  bf16x8 bfr[4];
#pragma unroll
  for (int k = 0; k < 4; ++k)
    bfr[k] = *(const bf16x8*)(ao +
        ((size_t)(bb * NPIX + p0 + n) * CIN + k * 32 + quad * 8));

  f32x4 acc[2];
#pragma unroll
  for (int mt = 0; mt < 2; ++mt) acc[mt] = (f32x4){0.f, 0.f, 0.f, 0.f};
#pragma unroll
  for (int k = 0; k < 4; ++k)
#pragma unroll
    for (int mt = 0; mt < 2; ++mt)
      acc[mt] = __builtin_amdgcn_mfma_f32_16x16x32_bf16(
          wf[mt][k], bfr[k], acc[mt], 0, 0, 0);

#pragma unroll
  for (int mt = 0; mt < 2; ++mt) {
    const int oc = oc0 + mt * 16 + quad * 4;
#pragma unroll
    for (int r = 0; r < 4; ++r)
      out[((size_t)bb * CIN + oc + r) * NPIX + p0 + n] =
          acc[mt][r] + bias[oc + r];
  }
}

// ---------------------------------------------------------------------------
extern "C" void kernel_launch(void* const* d_in, const int* in_sizes, int n_in,
                              void* d_out, int out_size, void* d_ws, size_t ws_size,
                              hipStream_t stream) {
  const float* x     = (const float*)d_in[0];   // [4,128,64,64]
  const float* w_qkv = (const float*)d_in[1];   // [384,128]
  const float* w_out = (const float*)d_in[2];   // [128,128]
  const float* b_out = (const float*)d_in[3];   // [128]
  float* out = (float*)d_out;                   // [4,128,64,64]

  // ws (bytes): qb 0 | kb 4M | vT 8M | ao 12M..16M  (16 MB total)
  char* base = (char*)d_ws;
  ushort* qb = (ushort*)base;
  ushort* kb = (ushort*)(base + (size_t)4 * 1024 * 1024);
  ushort* vT = (ushort*)(base + (size_t)8 * 1024 * 1024);
  ushort* ao = (ushort*)(base + (size_t)12 * 1024 * 1024);

  const float* xa = x; const float* wqa = w_qkv;
  const float* woa = w_out; const float* ba = b_out;
  ushort* qba = qb; ushort* kba = kb; ushort* vta = vT; ushort* aoa = ao;
  float* outa = out;
  void* kargs[] = {(void*)&xa, (void*)&wqa, (void*)&woa, (void*)&ba,
                   (void*)&qba, (void*)&kba, (void*)&vta, (void*)&aoa,
                   (void*)&outa};

  hipError_t err = hipLaunchCooperativeKernel(
      (const void*)fused_attn, dim3(512), dim3(256), kargs, 0, stream);
  if (err != hipSuccess) {
    (void)hipGetLastError();           // clear sticky error, use proven path
    qkv_mfma<<<dim3(512, 2), 256, 0, stream>>>(x, w_qkv, qb, kb, vT);
    flash_mfma<<<dim3(512), 256, 0, stream>>>(qb, kb, vT, ao);
    out_fused<<<dim3(1024), 256, 0, stream>>>(ao, w_out, b_out, out);
  }
}

// Round 9
// 133.235 us; speedup vs baseline: 1.8428x; 1.8428x over previous
//
#include <hip/hip_runtime.h>
#include <math.h>

#define NHEAD 4
#define DHEAD 32
#define NPIX  4096
#define CIN   128
#define RP    8   // query row-tiles per wave (128 queries) — proven optimum
#define PSTR  37  // LDS partial-row stride (f32); 37: 5 coprime 32 -> no 4-way

typedef __bf16 bf16_t;
typedef __bf16 bf16x8 __attribute__((ext_vector_type(8)));
typedef __bf16 bf16x4 __attribute__((ext_vector_type(4)));
typedef float  f32x4  __attribute__((ext_vector_type(4)));

// 1/sqrt(32) * log2(e): folded into q weights so softmax exp is bare exp2.
constexpr float QSCALE = 0.17677669529663687f * 1.4426950408889634f;

// ---------------------------------------------------------------------------
// QKV projection.  [r14 verbatim — prep_swz folded in, grid (512,2)]
// ---------------------------------------------------------------------------
__global__ void __launch_bounds__(256) qkv_mfma(
    const float* __restrict__ x, const float* __restrict__ wqkv,
    ushort* __restrict__ qb, ushort* __restrict__ kb, ushort* __restrict__ vT) {
  __shared__ ushort Xls[32 * 136];
  const int blk = blockIdx.x, tid = threadIdx.x;
  const int half = blockIdx.y;
  const int wave = tid >> 6, lane = tid & 63;
  const int n = lane & 15, quad = lane >> 4;
  const int bb = blk >> 7;             // batch
  const int p0 = (blk & 127) * 32;     // 32-px tile

  {  // stage x[bb][c][p0..p0+31] -> Xls[p][c] bf16 (4x4 transpose)
    const int pc = tid & 7, c0 = (tid >> 3) * 4;
    const float* xp = x + ((size_t)bb * CIN + c0) * NPIX + p0 + pc * 4;
    float4 r0 = *(const float4*)xp;
    float4 r1 = *(const float4*)(xp + NPIX);
    float4 r2 = *(const float4*)(xp + 2 * NPIX);
    float4 r3 = *(const float4*)(xp + 3 * NPIX);
    bf16x4 w0 = {(bf16_t)r0.x, (bf16_t)r1.x, (bf16_t)r2.x, (bf16_t)r3.x};
    bf16x4 w1 = {(bf16_t)r0.y, (bf16_t)r1.y, (bf16_t)r2.y, (bf16_t)r3.y};
    bf16x4 w2 = {(bf16_t)r0.z, (bf16_t)r1.z, (bf16_t)r2.z, (bf16_t)r3.z};
    bf16x4 w3 = {(bf16_t)r0.w, (bf16_t)r1.w, (bf16_t)r2.w, (bf16_t)r3.w};
    *(bf16x4*)&Xls[(pc * 4 + 0) * 136 + c0] = w0;
    *(bf16x4*)&Xls[(pc * 4 + 1) * 136 + c0] = w1;
    *(bf16x4*)&Xls[(pc * 4 + 2) * 136 + c0] = w2;
    *(bf16x4*)&Xls[(pc * 4 + 3) * 136 + c0] = w3;
  }
  __syncthreads();

  bf16x8 xf[2][4];                     // [px-tile nt][k]
#pragma unroll
  for (int nt = 0; nt < 2; ++nt)
#pragma unroll
    for (int k = 0; k < 4; ++k)
      xf[nt][k] = *(const bf16x8*)&Xls[(nt * 16 + n) * 136 + k * 32 + quad * 8];

#pragma unroll
  for (int mt = 0; mt < 3; ++mt) {     // wave covers 48 oc = 3 tiles
    const int ot = half * 12 + wave * 3 + mt;   // 0..23
    const int type = ot >> 3;          // 0=q 1=k 2=v
    const int wt = ot & 7, head = wt >> 1, d0 = (wt & 1) * 16;
    const int bh = bb * NHEAD + head;
    const float sc = (type == 0) ? QSCALE : 1.f;
    bf16x8 wf4[4];
#pragma unroll
    for (int k = 0; k < 4; ++k) {
      const float* ws = wqkv + (size_t)(ot * 16 + n) * CIN + k * 32 + quad * 8;
      float4 a = *(const float4*)ws;
      float4 b = *(const float4*)(ws + 4);
      wf4[k] = (bf16x8){(bf16_t)(a.x * sc), (bf16_t)(a.y * sc),
                        (bf16_t)(a.z * sc), (bf16_t)(a.w * sc),
                        (bf16_t)(b.x * sc), (bf16_t)(b.y * sc),
                        (bf16_t)(b.z * sc), (bf16_t)(b.w * sc)};
    }
    f32x4 acc[2] = {{0.f, 0.f, 0.f, 0.f}, {0.f, 0.f, 0.f, 0.f}};
    if (type < 2) {
#pragma unroll
      for (int k = 0; k < 4; ++k)
#pragma unroll
        for (int nt = 0; nt < 2; ++nt)
          acc[nt] = __builtin_amdgcn_mfma_f32_16x16x32_bf16(wf4[k], xf[nt][k], acc[nt], 0, 0, 0);
      ushort* dst = (type == 0) ? qb : kb;
#pragma unroll
      for (int nt = 0; nt < 2; ++nt) {  // C[m=oc][n=px] -> [p][d] b64
        bf16x4 o = {(bf16_t)acc[nt][0], (bf16_t)acc[nt][1],
                    (bf16_t)acc[nt][2], (bf16_t)acc[nt][3]};
        *(bf16x4*)(dst + ((size_t)bh * NPIX + p0 + nt * 16 + n) * DHEAD + d0 + quad * 4) = o;
      }
    } else {
#pragma unroll
      for (int k = 0; k < 4; ++k)
#pragma unroll
        for (int nt = 0; nt < 2; ++nt)
          acc[nt] = __builtin_amdgcn_mfma_f32_16x16x32_bf16(xf[nt][k], wf4[k], acc[nt], 0, 0, 0);
#pragma unroll
      for (int nt = 0; nt < 2; ++nt) {  // C[m=px][n=d] -> vT[d][p] b64
        bf16x4 o = {(bf16_t)acc[nt][0], (bf16_t)acc[nt][1],
                    (bf16_t)acc[nt][2], (bf16_t)acc[nt][3]};
        *(bf16x4*)(vT + ((size_t)bh * DHEAD + d0 + n) * NPIX + p0 + nt * 16 + quad * 4) = o;
      }
    }
  }
}

// ---------------------------------------------------------------------------
// Flash attention.  r19 = r17 (proven best: 47.9 us, intra-block key-split,
// WRITE 4 MB) + LDS partial stride 36 -> 37 f32 (5 coprime 32: kills the
// 147K 4-way bank conflicts in the combine-phase b128 reads).  Cooperative
// fusion refuted in r8 (grid.sync ~50 us each on 8 non-coherent XCDs).
// ---------------------------------------------------------------------------
__device__ __forceinline__ void ft_load(const ushort* kb0, const ushort* vb0,
                                        int t, bf16x8* kf, bf16x8* vf) {
#pragma unroll
  for (int p = 0; p < 2; ++p) {
#pragma unroll
    for (int s = 0; s < 2; ++s)
      kf[p * 2 + s] = *(const bf16x8*)(kb0 + (size_t)(t * 64 + p * 32 + s * 4) * DHEAD);
#pragma unroll
    for (int dp = 0; dp < 2; ++dp)
      vf[p * 2 + dp] = *(const bf16x8*)(vb0 + (size_t)dp * 16 * NPIX + t * 64 + p * 32);
  }
}

__device__ __forceinline__ void ft_compute(const bf16x8* qf, const bf16x8* kf,
                                           const bf16x8* vf, const bf16x8 ones,
                                           f32x4 O[RP][2], f32x4* Ol) {
  const f32x4 zero = {0.f, 0.f, 0.f, 0.f};
  __builtin_amdgcn_s_setprio(1);
#pragma unroll
  for (int p = 0; p < 2; ++p) {
#pragma unroll
    for (int rp = 0; rp < RP; ++rp) {
      f32x4 sa = __builtin_amdgcn_mfma_f32_16x16x32_bf16(kf[p * 2 + 0], qf[rp], zero, 0, 0, 0);
      f32x4 sb = __builtin_amdgcn_mfma_f32_16x16x32_bf16(kf[p * 2 + 1], qf[rp], zero, 0, 0, 0);
      bf16x8 pf;
#pragma unroll
      for (int r = 0; r < 4; ++r) {
        pf[r]     = (bf16_t)__builtin_amdgcn_exp2f(sa[r]);
        pf[r + 4] = (bf16_t)__builtin_amdgcn_exp2f(sb[r]);
      }
      O[rp][0] = __builtin_amdgcn_mfma_f32_16x16x32_bf16(pf, vf[p * 2 + 0], O[rp][0], 0, 0, 0);
      O[rp][1] = __builtin_amdgcn_mfma_f32_16x16x32_bf16(pf, vf[p * 2 + 1], O[rp][1], 0, 0, 0);
      Ol[rp]   = __builtin_amdgcn_mfma_f32_16x16x32_bf16(pf, ones, Ol[rp], 0, 0, 0);
    }
  }
  __builtin_amdgcn_s_setprio(0);
}

__global__ void __launch_bounds__(256, 2) flash_mfma(
    const ushort* __restrict__ qb, const ushort* __restrict__ kbuf,
    const ushort* __restrict__ vTb, ushort* __restrict__ ao) {
  __shared__ float Ols[4 * 128 * PSTR];  // [wave][q][d0..31, l@32] (75.8 KB)
  const int tid = threadIdx.x, wave = tid >> 6, lane = tid & 63;
  const int n = lane & 15, quad = lane >> 4;

  const int id = blockIdx.x;
  const int bh = id & 15;              // id%8 == bh%8 -> per-bh XCD affinity
  const int qblk = id >> 4;            // 0..31
  const int js = wave;                 // intra-block key split
  const int qrel = qblk * 128;

  const ushort* kg = kbuf + (size_t)bh * NPIX * DHEAD;
  const ushort* vg = vTb + (size_t)bh * DHEAD * NPIX;

  bf16x8 qf[RP];
#pragma unroll
  for (int rp = 0; rp < RP; ++rp)
    qf[rp] = *(const bf16x8*)(qb +
        ((size_t)bh * NPIX + qrel + rp * 16 + n) * DHEAD + quad * 8);

  f32x4 O[RP][2], Ol[RP];
#pragma unroll
  for (int rp = 0; rp < RP; ++rp) {
    O[rp][0] = (f32x4){0.f, 0.f, 0.f, 0.f};
    O[rp][1] = (f32x4){0.f, 0.f, 0.f, 0.f};
    Ol[rp]   = (f32x4){0.f, 0.f, 0.f, 0.f};
  }
  const bf16_t one = (bf16_t)1.0f;
  const bf16x8 ones = {one, one, one, one, one, one, one, one};

  // permuted K row: pi(n) = (n>>2)*8 + (n&3); quad gives the d-offset
  const int pk = ((n >> 2) << 3) | (n & 3);
  const ushort* kb0 = kg + (size_t)(js * 1024 + pk) * DHEAD + quad * 8;
  const ushort* vb0 = vg + (size_t)n * NPIX + js * 1024 + quad * 8;

  bf16x8 kA[4], vA[4], kB[4], vB[4];
  ft_load(kb0, vb0, 0, kA, vA);
#pragma unroll 1
  for (int t = 0; t < 16; t += 2) {
    ft_load(kb0, vb0, t + 1, kB, vB);
    ft_compute(qf, kA, vA, ones, O, Ol);
    if (t + 2 < 16) ft_load(kb0, vb0, t + 2, kA, vA);
    ft_compute(qf, kB, vB, ones, O, Ol);
  }

  // partials -> LDS (stride PSTR f32; O at +0..31, l at +32)
  {
    float* pb = &Ols[wave * 128 * PSTR];
#pragma unroll
    for (int rp = 0; rp < RP; ++rp)
#pragma unroll
      for (int r = 0; r < 4; ++r) {
        const int q = rp * 16 + quad * 4 + r;
        pb[q * PSTR + n]      = O[rp][0][r];
        pb[q * PSTR + 16 + n] = O[rp][1][r];
        if (n == 0) pb[q * PSTR + 32] = Ol[rp][r];
      }
  }
  __syncthreads();

  // combine 4 wave-partials, normalize, cast, store bf16 ao
  {
    const int q = tid >> 1, dh = tid & 1;
    f32x4 A0 = {0.f, 0.f, 0.f, 0.f}, A1 = A0, A2 = A0, A3 = A0;
    float l = 0.f;
#pragma unroll
    for (int w = 0; w < 4; ++w) {
      const float* pp = &Ols[(w * 128 + q) * PSTR + dh * 16];
      A0 += *(const f32x4*)pp;
      A1 += *(const f32x4*)(pp + 4);
      A2 += *(const f32x4*)(pp + 8);
      A3 += *(const f32x4*)(pp + 12);
      l += pp[32 - dh * 16];
    }
    const float inv = 1.f / l;
    bf16x8 o0, o1;
#pragma unroll
    for (int e = 0; e < 4; ++e) {
      o0[e]     = (bf16_t)(A0[e] * inv);
      o0[e + 4] = (bf16_t)(A1[e] * inv);
      o1[e]     = (bf16_t)(A2[e] * inv);
      o1[e + 4] = (bf16_t)(A3[e] * inv);
    }
    ushort* dst = ao + ((size_t)((bh >> 2) * NPIX + qrel + q) * CIN
                        + (bh & 3) * 32 + dh * 16);
    *(bf16x8*)dst = o0;
    *(bf16x8*)(dst + 8) = o1;
  }
}

// ---------------------------------------------------------------------------
// out_fused.  [r17 verbatim — reads final bf16 ao directly, pure projection]
// ---------------------------------------------------------------------------
__global__ void __launch_bounds__(256) out_fused(
    const ushort* __restrict__ ao, const float* __restrict__ wout,
    const float* __restrict__ bias, float* __restrict__ out) {
  const int blk = blockIdx.x, tid = threadIdx.x;
  const int wave = tid >> 6, lane = tid & 63;
  const int n = lane & 15, quad = lane >> 4;
  const int bb = blk >> 8;
  const int p0 = (blk & 255) * 16;
  const int oc0 = wave * 32;

  bf16x8 wf[2][4];
#pragma unroll
  for (int mt = 0; mt < 2; ++mt)
#pragma unroll
    for (int k = 0; k < 4; ++k) {
      const float* ws = wout + (size_t)((wave * 2 + mt) * 16 + n) * CIN + k * 32 + quad * 8;
      float4 a = *(const float4*)ws;
      float4 b = *(const float4*)(ws + 4);
      wf[mt][k] = (bf16x8){(bf16_t)a.x, (bf16_t)a.y, (bf16_t)a.z, (bf16_t)a.w,
                           (bf16_t)b.x, (bf16_t)b.y, (bf16_t)b.z, (bf16_t)b.w};
    }

  bf16x8 bfr[4];                       // [k] straight from global ao
#pragma unroll
  for (int k = 0; k < 4; ++k)
    bfr[k] = *(const bf16x8*)(ao +
        ((size_t)(bb * NPIX + p0 + n) * CIN + k * 32 + quad * 8));

  f32x4 acc[2];
#pragma unroll
  for (int mt = 0; mt < 2; ++mt) acc[mt] = (f32x4){0.f, 0.f, 0.f, 0.f};
#pragma unroll
  for (int k = 0; k < 4; ++k)
#pragma unroll
    for (int mt = 0; mt < 2; ++mt)
      acc[mt] = __builtin_amdgcn_mfma_f32_16x16x32_bf16(
          wf[mt][k], bfr[k], acc[mt], 0, 0, 0);

#pragma unroll
  for (int mt = 0; mt < 2; ++mt) {
    const int oc = oc0 + mt * 16 + quad * 4;
#pragma unroll
    for (int r = 0; r < 4; ++r)
      out[((size_t)bb * CIN + oc + r) * NPIX + p0 + n] =
          acc[mt][r] + bias[oc + r];
  }
}

// ---------------------------------------------------------------------------
extern "C" void kernel_launch(void* const* d_in, const int* in_sizes, int n_in,
                              void* d_out, int out_size, void* d_ws, size_t ws_size,
                              hipStream_t stream) {
  const float* x     = (const float*)d_in[0];   // [4,128,64,64]
  const float* w_qkv = (const float*)d_in[1];   // [384,128]
  const float* w_out = (const float*)d_in[2];   // [128,128]
  const float* b_out = (const float*)d_in[3];   // [128]
  float* out = (float*)d_out;                   // [4,128,64,64]

  // ws (bytes): qb 0 | kb 4M | vT 8M | ao 12M..16M  (16 MB total)
  char* base = (char*)d_ws;
  ushort* qb = (ushort*)base;
  ushort* kb = (ushort*)(base + (size_t)4 * 1024 * 1024);
  ushort* vT = (ushort*)(base + (size_t)8 * 1024 * 1024);
  ushort* ao = (ushort*)(base + (size_t)12 * 1024 * 1024);

  qkv_mfma<<<dim3(512, 2), 256, 0, stream>>>(x, w_qkv, qb, kb, vT);
  flash_mfma<<<dim3(512), 256, 0, stream>>>(qb, kb, vT, ao);
  out_fused<<<dim3(1024), 256, 0, stream>>>(ao, w_out, b_out, out);
}

// Round 10
// 130.774 us; speedup vs baseline: 1.8775x; 1.0188x over previous
//
#include <hip/hip_runtime.h>
#include <math.h>

#define NHEAD 4
#define DHEAD 32
#define NPIX  4096
#define CIN   128
#define RP    8   // query row-tiles per wave (128 queries) — proven optimum

typedef __bf16 bf16_t;
typedef __bf16 bf16x8 __attribute__((ext_vector_type(8)));
typedef __bf16 bf16x4 __attribute__((ext_vector_type(4)));
typedef float  f32x4  __attribute__((ext_vector_type(4)));

// 1/sqrt(32) * log2(e): folded into q weights so softmax exp is bare exp2.
constexpr float QSCALE = 0.17677669529663687f * 1.4426950408889634f;

// ---------------------------------------------------------------------------
// QKV projection.  [r14 verbatim — prep_swz folded in, grid (512,2)]
// ---------------------------------------------------------------------------
__global__ void __launch_bounds__(256) qkv_mfma(
    const float* __restrict__ x, const float* __restrict__ wqkv,
    ushort* __restrict__ qb, ushort* __restrict__ kb, ushort* __restrict__ vT) {
  __shared__ ushort Xls[32 * 136];
  const int blk = blockIdx.x, tid = threadIdx.x;
  const int half = blockIdx.y;
  const int wave = tid >> 6, lane = tid & 63;
  const int n = lane & 15, quad = lane >> 4;
  const int bb = blk >> 7;             // batch
  const int p0 = (blk & 127) * 32;     // 32-px tile

  {  // stage x[bb][c][p0..p0+31] -> Xls[p][c] bf16 (4x4 transpose)
    const int pc = tid & 7, c0 = (tid >> 3) * 4;
    const float* xp = x + ((size_t)bb * CIN + c0) * NPIX + p0 + pc * 4;
    float4 r0 = *(const float4*)xp;
    float4 r1 = *(const float4*)(xp + NPIX);
    float4 r2 = *(const float4*)(xp + 2 * NPIX);
    float4 r3 = *(const float4*)(xp + 3 * NPIX);
    bf16x4 w0 = {(bf16_t)r0.x, (bf16_t)r1.x, (bf16_t)r2.x, (bf16_t)r3.x};
    bf16x4 w1 = {(bf16_t)r0.y, (bf16_t)r1.y, (bf16_t)r2.y, (bf16_t)r3.y};
    bf16x4 w2 = {(bf16_t)r0.z, (bf16_t)r1.z, (bf16_t)r2.z, (bf16_t)r3.z};
    bf16x4 w3 = {(bf16_t)r0.w, (bf16_t)r1.w, (bf16_t)r2.w, (bf16_t)r3.w};
    *(bf16x4*)&Xls[(pc * 4 + 0) * 136 + c0] = w0;
    *(bf16x4*)&Xls[(pc * 4 + 1) * 136 + c0] = w1;
    *(bf16x4*)&Xls[(pc * 4 + 2) * 136 + c0] = w2;
    *(bf16x4*)&Xls[(pc * 4 + 3) * 136 + c0] = w3;
  }
  __syncthreads();

  bf16x8 xf[2][4];                     // [px-tile nt][k]
#pragma unroll
  for (int nt = 0; nt < 2; ++nt)
#pragma unroll
    for (int k = 0; k < 4; ++k)
      xf[nt][k] = *(const bf16x8*)&Xls[(nt * 16 + n) * 136 + k * 32 + quad * 8];

#pragma unroll
  for (int mt = 0; mt < 3; ++mt) {     // wave covers 48 oc = 3 tiles
    const int ot = half * 12 + wave * 3 + mt;   // 0..23
    const int type = ot >> 3;          // 0=q 1=k 2=v
    const int wt = ot & 7, head = wt >> 1, d0 = (wt & 1) * 16;
    const int bh = bb * NHEAD + head;
    const float sc = (type == 0) ? QSCALE : 1.f;
    bf16x8 wf4[4];
#pragma unroll
    for (int k = 0; k < 4; ++k) {
      const float* ws = wqkv + (size_t)(ot * 16 + n) * CIN + k * 32 + quad * 8;
      float4 a = *(const float4*)ws;
      float4 b = *(const float4*)(ws + 4);
      wf4[k] = (bf16x8){(bf16_t)(a.x * sc), (bf16_t)(a.y * sc),
                        (bf16_t)(a.z * sc), (bf16_t)(a.w * sc),
                        (bf16_t)(b.x * sc), (bf16_t)(b.y * sc),
                        (bf16_t)(b.z * sc), (bf16_t)(b.w * sc)};
    }
    f32x4 acc[2] = {{0.f, 0.f, 0.f, 0.f}, {0.f, 0.f, 0.f, 0.f}};
    if (type < 2) {
#pragma unroll
      for (int k = 0; k < 4; ++k)
#pragma unroll
        for (int nt = 0; nt < 2; ++nt)
          acc[nt] = __builtin_amdgcn_mfma_f32_16x16x32_bf16(wf4[k], xf[nt][k], acc[nt], 0, 0, 0);
      ushort* dst = (type == 0) ? qb : kb;
#pragma unroll
      for (int nt = 0; nt < 2; ++nt) {  // C[m=oc][n=px] -> [p][d] b64
        bf16x4 o = {(bf16_t)acc[nt][0], (bf16_t)acc[nt][1],
                    (bf16_t)acc[nt][2], (bf16_t)acc[nt][3]};
        *(bf16x4*)(dst + ((size_t)bh * NPIX + p0 + nt * 16 + n) * DHEAD + d0 + quad * 4) = o;
      }
    } else {
#pragma unroll
      for (int k = 0; k < 4; ++k)
#pragma unroll
        for (int nt = 0; nt < 2; ++nt)
          acc[nt] = __builtin_amdgcn_mfma_f32_16x16x32_bf16(xf[nt][k], wf4[k], acc[nt], 0, 0, 0);
#pragma unroll
      for (int nt = 0; nt < 2; ++nt) {  // C[m=px][n=d] -> vT[d][p] b64
        bf16x4 o = {(bf16_t)acc[nt][0], (bf16_t)acc[nt][1],
                    (bf16_t)acc[nt][2], (bf16_t)acc[nt][3]};
        *(bf16x4*)(vT + ((size_t)bh * DHEAD + d0 + n) * NPIX + p0 + nt * 16 + quad * 4) = o;
      }
    }
  }
}

// ---------------------------------------------------------------------------
// Flash attention.  r20 = r17 verbatim (proven best: 47.9 us).  PSTR=37
// padding refuted in r9 (conflicts up, writes de-optimized; total conflict
// cost ~0.2 us — immaterial).  Stride 36 restored: write phase is 2-way
// (free), combine-read 4-way on a tiny phase.
// ---------------------------------------------------------------------------
__device__ __forceinline__ void ft_load(const ushort* kb0, const ushort* vb0,
                                        int t, bf16x8* kf, bf16x8* vf) {
#pragma unroll
  for (int p = 0; p < 2; ++p) {
#pragma unroll
    for (int s = 0; s < 2; ++s)
      kf[p * 2 + s] = *(const bf16x8*)(kb0 + (size_t)(t * 64 + p * 32 + s * 4) * DHEAD);
#pragma unroll
    for (int dp = 0; dp < 2; ++dp)
      vf[p * 2 + dp] = *(const bf16x8*)(vb0 + (size_t)dp * 16 * NPIX + t * 64 + p * 32);
  }
}

__device__ __forceinline__ void ft_compute(const bf16x8* qf, const bf16x8* kf,
                                           const bf16x8* vf, const bf16x8 ones,
                                           f32x4 O[RP][2], f32x4* Ol) {
  const f32x4 zero = {0.f, 0.f, 0.f, 0.f};
  __builtin_amdgcn_s_setprio(1);
#pragma unroll
  for (int p = 0; p < 2; ++p) {
#pragma unroll
    for (int rp = 0; rp < RP; ++rp) {
      f32x4 sa = __builtin_amdgcn_mfma_f32_16x16x32_bf16(kf[p * 2 + 0], qf[rp], zero, 0, 0, 0);
      f32x4 sb = __builtin_amdgcn_mfma_f32_16x16x32_bf16(kf[p * 2 + 1], qf[rp], zero, 0, 0, 0);
      bf16x8 pf;
#pragma unroll
      for (int r = 0; r < 4; ++r) {
        pf[r]     = (bf16_t)__builtin_amdgcn_exp2f(sa[r]);
        pf[r + 4] = (bf16_t)__builtin_amdgcn_exp2f(sb[r]);
      }
      O[rp][0] = __builtin_amdgcn_mfma_f32_16x16x32_bf16(pf, vf[p * 2 + 0], O[rp][0], 0, 0, 0);
      O[rp][1] = __builtin_amdgcn_mfma_f32_16x16x32_bf16(pf, vf[p * 2 + 1], O[rp][1], 0, 0, 0);
      Ol[rp]   = __builtin_amdgcn_mfma_f32_16x16x32_bf16(pf, ones, Ol[rp], 0, 0, 0);
    }
  }
  __builtin_amdgcn_s_setprio(0);
}

__global__ void __launch_bounds__(256, 2) flash_mfma(
    const ushort* __restrict__ qb, const ushort* __restrict__ kbuf,
    const ushort* __restrict__ vTb, ushort* __restrict__ ao) {
  __shared__ float Ols[4 * 128 * 36];   // [wave][q][d0..31, l@32] (73.7 KB)
  const int tid = threadIdx.x, wave = tid >> 6, lane = tid & 63;
  const int n = lane & 15, quad = lane >> 4;

  const int id = blockIdx.x;
  const int bh = id & 15;              // id%8 == bh%8 -> per-bh XCD affinity
  const int qblk = id >> 4;            // 0..31
  const int js = wave;                 // intra-block key split
  const int qrel = qblk * 128;

  const ushort* kg = kbuf + (size_t)bh * NPIX * DHEAD;
  const ushort* vg = vTb + (size_t)bh * DHEAD * NPIX;

  bf16x8 qf[RP];
#pragma unroll
  for (int rp = 0; rp < RP; ++rp)
    qf[rp] = *(const bf16x8*)(qb +
        ((size_t)bh * NPIX + qrel + rp * 16 + n) * DHEAD + quad * 8);

  f32x4 O[RP][2], Ol[RP];
#pragma unroll
  for (int rp = 0; rp < RP; ++rp) {
    O[rp][0] = (f32x4){0.f, 0.f, 0.f, 0.f};
    O[rp][1] = (f32x4){0.f, 0.f, 0.f, 0.f};
    Ol[rp]   = (f32x4){0.f, 0.f, 0.f, 0.f};
  }
  const bf16_t one = (bf16_t)1.0f;
  const bf16x8 ones = {one, one, one, one, one, one, one, one};

  // permuted K row: pi(n) = (n>>2)*8 + (n&3); quad gives the d-offset
  const int pk = ((n >> 2) << 3) | (n & 3);
  const ushort* kb0 = kg + (size_t)(js * 1024 + pk) * DHEAD + quad * 8;
  const ushort* vb0 = vg + (size_t)n * NPIX + js * 1024 + quad * 8;

  bf16x8 kA[4], vA[4], kB[4], vB[4];
  ft_load(kb0, vb0, 0, kA, vA);
#pragma unroll 1
  for (int t = 0; t < 16; t += 2) {
    ft_load(kb0, vb0, t + 1, kB, vB);
    ft_compute(qf, kA, vA, ones, O, Ol);
    if (t + 2 < 16) ft_load(kb0, vb0, t + 2, kA, vA);
    ft_compute(qf, kB, vB, ones, O, Ol);
  }

  // partials -> LDS (layout identical to old global 'part' rows)
  {
    float* pb = &Ols[wave * 128 * 36];
#pragma unroll
    for (int rp = 0; rp < RP; ++rp)
#pragma unroll
      for (int r = 0; r < 4; ++r) {
        const int q = rp * 16 + quad * 4 + r;
        pb[q * 36 + n]      = O[rp][0][r];
        pb[q * 36 + 16 + n] = O[rp][1][r];
        if (n == 0) pb[q * 36 + 32] = Ol[rp][r];
      }
  }
  __syncthreads();

  // combine 4 wave-partials, normalize, cast, store bf16 ao
  {
    const int q = tid >> 1, dh = tid & 1;
    f32x4 A0 = {0.f, 0.f, 0.f, 0.f}, A1 = A0, A2 = A0, A3 = A0;
    float l = 0.f;
#pragma unroll
    for (int w = 0; w < 4; ++w) {
      const float* pp = &Ols[(w * 128 + q) * 36 + dh * 16];
      A0 += *(const f32x4*)pp;
      A1 += *(const f32x4*)(pp + 4);
      A2 += *(const f32x4*)(pp + 8);
      A3 += *(const f32x4*)(pp + 12);
      l += pp[32 - dh * 16];
    }
    const float inv = 1.f / l;
    bf16x8 o0, o1;
#pragma unroll
    for (int e = 0; e < 4; ++e) {
      o0[e]     = (bf16_t)(A0[e] * inv);
      o0[e + 4] = (bf16_t)(A1[e] * inv);
      o1[e]     = (bf16_t)(A2[e] * inv);
      o1[e + 4] = (bf16_t)(A3[e] * inv);
    }
    ushort* dst = ao + ((size_t)((bh >> 2) * NPIX + qrel + q) * CIN
                        + (bh & 3) * 32 + dh * 16);
    *(bf16x8*)dst = o0;
    *(bf16x8*)(dst + 8) = o1;
  }
}

// ---------------------------------------------------------------------------
// out_fused.  [r17 verbatim — reads final bf16 ao directly, pure projection]
// ---------------------------------------------------------------------------
__global__ void __launch_bounds__(256) out_fused(
    const ushort* __restrict__ ao, const float* __restrict__ wout,
    const float* __restrict__ bias, float* __restrict__ out) {
  const int blk = blockIdx.x, tid = threadIdx.x;
  const int wave = tid >> 6, lane = tid & 63;
  const int n = lane & 15, quad = lane >> 4;
  const int bb = blk >> 8;
  const int p0 = (blk & 255) * 16;
  const int oc0 = wave * 32;

  bf16x8 wf[2][4];
#pragma unroll
  for (int mt = 0; mt < 2; ++mt)
#pragma unroll
    for (int k = 0; k < 4; ++k) {
      const float* ws = wout + (size_t)((wave * 2 + mt) * 16 + n) * CIN + k * 32 + quad * 8;
      float4 a = *(const float4*)ws;
      float4 b = *(const float4*)(ws + 4);
      wf[mt][k] = (bf16x8){(bf16_t)a.x, (bf16_t)a.y, (bf16_t)a.z, (bf16_t)a.w,
                           (bf16_t)b.x, (bf16_t)b.y, (bf16_t)b.z, (bf16_t)b.w};
    }

  bf16x8 bfr[4];                       // [k] straight from global ao
#pragma unroll
  for (int k = 0; k < 4; ++k)
    bfr[k] = *(const bf16x8*)(ao +
        ((size_t)(bb * NPIX + p0 + n) * CIN + k * 32 + quad * 8));

  f32x4 acc[2];
#pragma unroll
  for (int mt = 0; mt < 2; ++mt) acc[mt] = (f32x4){0.f, 0.f, 0.f, 0.f};
#pragma unroll
  for (int k = 0; k < 4; ++k)
#pragma unroll
    for (int mt = 0; mt < 2; ++mt)
      acc[mt] = __builtin_amdgcn_mfma_f32_16x16x32_bf16(
          wf[mt][k], bfr[k], acc[mt], 0, 0, 0);

#pragma unroll
  for (int mt = 0; mt < 2; ++mt) {
    const int oc = oc0 + mt * 16 + quad * 4;
#pragma unroll
    for (int r = 0; r < 4; ++r)
      out[((size_t)bb * CIN + oc + r) * NPIX + p0 + n] =
          acc[mt][r] + bias[oc + r];
  }
}

// ---------------------------------------------------------------------------
extern "C" void kernel_launch(void* const* d_in, const int* in_sizes, int n_in,
                              void* d_out, int out_size, void* d_ws, size_t ws_size,
                              hipStream_t stream) {
  const float* x     = (const float*)d_in[0];   // [4,128,64,64]
  const float* w_qkv = (const float*)d_in[1];   // [384,128]
  const float* w_out = (const float*)d_in[2];   // [128,128]
  const float* b_out = (const float*)d_in[3];   // [128]
  float* out = (float*)d_out;                   // [4,128,64,64]

  // ws (bytes): qb 0 | kb 4M | vT 8M | ao 12M..16M  (16 MB total)
  char* base = (char*)d_ws;
  ushort* qb = (ushort*)base;
  ushort* kb = (ushort*)(base + (size_t)4 * 1024 * 1024);
  ushort* vT = (ushort*)(base + (size_t)8 * 1024 * 1024);
  ushort* ao = (ushort*)(base + (size_t)12 * 1024 * 1024);

  qkv_mfma<<<dim3(512, 2), 256, 0, stream>>>(x, w_qkv, qb, kb, vT);
  flash_mfma<<<dim3(512), 256, 0, stream>>>(qb, kb, vT, ao);
  out_fused<<<dim3(1024), 256, 0, stream>>>(ao, w_out, b_out, out);
}